// Round 9
// baseline (35.684 us; speedup 1.0000x reference)
//
#include <hip/hip_runtime.h>

#define DENSE_L 20
#define LT 16
#define BLOCK 256
#define KQ 4                   // k-outputs per quarter pass
#define NPASS (LT / KQ)        // 4
#define GPP (DENSE_L * KQ)     // 80 G floats per pass = 5 x 64B uniform loads
#define OPAD 20                // padded out-stage row (dwords): 2-way banks, 16B-aligned

typedef float v4f  __attribute__((ext_vector_type(4)));
typedef float v16f __attribute__((ext_vector_type(16)));

// Precompute G transposed: Gt[k*20 + t] = exp(-((t+1)-w_k)^2 / std^2).
__global__ void g_precompute(const float* __restrict__ weight, float* __restrict__ Gt)
{
    int i = threadIdx.x;               // 320 threads
    if (i < DENSE_L * LT) {
        int k = i / DENSE_L;
        int t = i - k * DENSE_L;
        float d = (float)(t + 1) - weight[k];
        Gt[i] = __expf(-d * d * 6.25f);    // 1/std^2 = 6.25
    }
}

// Direct global->LDS DMA, 16B per lane. Layout requirement (wave-uniform base +
// lane*16, contiguous) is satisfied: dest index = tid + 256*j is lane-linear.
__device__ inline void async_copy16(const float* g, float* l)
{
    __builtin_amdgcn_global_load_lds(
        (const __attribute__((address_space(1))) void*)g,
        (__attribute__((address_space(3))) void*)l,
        16 /* literal bytes */, 0, 0);
}

// R8 (35.5us, best) proved the limiter was the 80B-strided per-lane x access;
// LDS staging fixed it. R9: (a) x-stage via global_load_lds (no VGPR round-trip
// -- compiler never auto-emits this), (b) disjoint x/out LDS regions remove one
// barrier. Frozen from prior evidence: rolled SGPR-G quarters (R6), bulk
// coalesced I/O (R0/R8), regular stores (NT amplified writes 1.8x, R4/R7),
// no launch_bounds min-waves hint (R2/R3 spills).
__global__ __launch_bounds__(BLOCK) void sampling_kernel(
    const float* __restrict__ x, const float* __restrict__ Gt,
    float* __restrict__ out, int nrows)
{
    __shared__ float xs[BLOCK * DENSE_L];   // 20 KB x stage
    __shared__ float os[BLOCK * OPAD];      // 20 KB out stage (disjoint)

    const int tid = threadIdx.x;
    const size_t blockRow = (size_t)blockIdx.x * BLOCK;

    // ---- coalesced x load, direct to LDS: 5 x global_load_lds_dwordx4 ----
    {
        const float* src = x + blockRow * DENSE_L;
        #pragma unroll
        for (int j = 0; j < 5; ++j) {
            int f = tid + BLOCK * j;            // float4 index in 20KB tile
            async_copy16(src + 4 * f, xs + 4 * f);
        }
    }
    __syncthreads();   // compiler emits vmcnt(0) drain before s_barrier

    // ---- each thread pulls its own row (5 x ds_read_b128, 2-way = free) ----
    float xv[DENSE_L];
    #pragma unroll
    for (int j = 0; j < 5; ++j) {
        float4 v = *reinterpret_cast<const float4*>(&xs[tid * DENSE_L + 4 * j]);
        xv[4*j+0] = v.x; xv[4*j+1] = v.y; xv[4*j+2] = v.z; xv[4*j+3] = v.w;
    }
    // no barrier needed: out-stage is a disjoint LDS region

    // ---- 4 rolled k-quarter passes; G uniform-loaded into SGPRs ----
    #pragma unroll 1
    for (int p = 0; p < NPASS; ++p) {
        const v16f* gq = reinterpret_cast<const v16f*>(Gt + p * GPP);
        v16f q[5] = {gq[0], gq[1], gq[2], gq[3], gq[4]};

        float a[KQ] = {0.f, 0.f, 0.f, 0.f};
        #pragma unroll
        for (int kk = 0; kk < KQ; ++kk) {
            #pragma unroll
            for (int t = 0; t < DENSE_L; ++t) {
                int gi = kk * DENSE_L + t;            // compile-time after unroll
                a[kk] += xv[t] * q[gi >> 4][gi & 15]; // v_fmac v,s,v
            }
        }
        *reinterpret_cast<v4f*>(&os[tid * OPAD + 4 * p]) = (v4f){a[0], a[1], a[2], a[3]};
    }
    __syncthreads();

    // ---- coalesced out store: full 64B lines, regular stores ----
    {
        float4* po = reinterpret_cast<float4*>(out + blockRow * LT);
        #pragma unroll
        for (int j = 0; j < 4; ++j) {
            int g = tid + BLOCK * j;                 // global float4 index in tile
            int r = g >> 2, s = g & 3;               // out row / sub-quad
            po[g] = *reinterpret_cast<const float4*>(&os[r * OPAD + 4 * s]);
        }
    }
}

extern "C" void kernel_launch(void* const* d_in, const int* in_sizes, int n_in,
                              void* d_out, int out_size, void* d_ws, size_t ws_size,
                              hipStream_t stream) {
    const float* x = (const float*)d_in[0];
    const float* w = (const float*)d_in[1];
    float* out = (float*)d_out;
    float* Gt = (float*)d_ws;                // 320 floats = 1280 B workspace
    int nrows = in_sizes[0] / DENSE_L;       // 1,048,576 (divisible by 256)

    g_precompute<<<1, 320, 0, stream>>>(w, Gt);

    int grid = nrows / BLOCK;                // 4096 full blocks
    sampling_kernel<<<grid, BLOCK, 0, stream>>>(x, Gt, out, nrows);
}